// Round 5
// baseline (2346.055 us; speedup 1.0000x reference)
//
#include <hip/hip_runtime.h>
#include <hip/hip_bf16.h>
#include <math.h>

#define N_NODES 100000
#define E_EDGES 3200000
#define IN_DIM  256

typedef __attribute__((ext_vector_type(8))) short bf16x8;
typedef __attribute__((ext_vector_type(4))) float f32x4;

// ---- bf16 helpers ---------------------------------------------------------
__device__ __forceinline__ unsigned short f2bf(float f) {
  unsigned u = __float_as_uint(f);
  u += 0x7fffu + ((u >> 16) & 1u);   // RTNE
  return (unsigned short)(u >> 16);
}
__device__ __forceinline__ float bf2f(unsigned short h) {
  return __uint_as_float(((unsigned)h) << 16);
}

// ---------------- BN column stats ------------------------------------------
__global__ __launch_bounds__(256) void bn_stats_kernel(
    const float* __restrict__ x, float* __restrict__ sums) {
  int c = threadIdx.x;
  float s = 0.f, s2 = 0.f;
  for (int r = blockIdx.x; r < N_NODES; r += gridDim.x) {
    float v = x[(size_t)r * IN_DIM + c];
    s += v; s2 += v * v;
  }
  atomicAdd(&sums[c], s);
  atomicAdd(&sums[256 + c], s2);
}

// ------------- fold BN affine into W_in / b_in ----------------------------
__global__ __launch_bounds__(256) void fold_bn_kernel(
    const float* __restrict__ sums, const float* __restrict__ bn_g,
    const float* __restrict__ bn_b, const float* __restrict__ W_in,
    const float* __restrict__ b_in, float* __restrict__ Wf,
    float* __restrict__ bf) {
  int j = blockIdx.x;   // out col 0..139
  int c = threadIdx.x;  // in col 0..255
  const float invN = 1.0f / (float)N_NODES;
  float mu  = sums[c] * invN;
  float var = sums[256 + c] * invN - mu * mu;
  float s   = bn_g[c] * rsqrtf(var + 1e-5f);
  float t   = bn_b[c] - mu * s;
  float w   = W_in[(size_t)c * 140 + j];
  Wf[(size_t)c * 140 + j] = s * w;
  float v = t * w;
  for (int o = 32; o > 0; o >>= 1) v += __shfl_down(v, o, 64);
  __shared__ float red[4];
  int wid = threadIdx.x >> 6, lane = threadIdx.x & 63;
  if (lane == 0) red[wid] = v;
  __syncthreads();
  if (threadIdx.x == 0)
    bf[j] = b_in[j] + red[0] + red[1] + red[2] + red[3];
}

// ---------------- CSR row_ptr from sorted rows -----------------------------
__global__ __launch_bounds__(256) void build_rowptr_kernel(
    const int* __restrict__ rows, int* __restrict__ rowptr) {
  int r = blockIdx.x * 256 + threadIdx.x;
  if (r > N_NODES) return;
  int lo = 0, hi = E_EDGES;
  while (lo < hi) {
    int mid = (lo + hi) >> 1;
    if (rows[mid] < r) lo = mid + 1; else hi = mid;
  }
  rowptr[r] = lo;
}

// ---------------- pack edges: col<<15 | q15(val) ---------------------------
__global__ __launch_bounds__(256) void pack_edges_kernel(
    const int* __restrict__ cols, const float* __restrict__ vals,
    unsigned* __restrict__ ep) {
  int e = blockIdx.x * 256 + threadIdx.x;
  if (e >= E_EDGES) return;
  unsigned q = (unsigned)(vals[e] * 32767.f + 0.5f);
  if (q > 32767u) q = 32767u;
  ep[e] = ((unsigned)cols[e] << 15) | q;
}

// ------- pack fp32 W[K,M] into MFMA B-fragment order, bf16, zero-padded ----
__global__ __launch_bounds__(256) void pack_w_kernel(
    const float* __restrict__ W, uint4* __restrict__ Bp, int K, int M, int NT,
    int total) {
  int id = blockIdx.x * 256 + threadIdx.x;
  if (id >= total) return;
  int lane = id & 63;
  int nt = (id >> 6) % NT;
  int kt = id / (64 * NT);
  int n = nt * 16 + (lane & 15);
  int kbase = kt * 32 + (lane >> 4) * 8;
  unsigned short v[8];
#pragma unroll
  for (int j = 0; j < 8; ++j) {
    int k = kbase + j;
    v[j] = (k < K && n < M) ? f2bf(W[(size_t)k * M + n]) : (unsigned short)0;
  }
  Bp[id] = *(uint4*)v;
}

// ---------------- MFMA bf16 GEMM -------------------------------------------
// outfmt: 0 fp32 flat, 1 bf16 flat, 2 bf16 chunked [chunk][N][16]
template <int KPAD, int NT, typename AT>
__global__ __launch_bounds__(256) void mfma_gemm_kernel(
    const AT* __restrict__ A, const uint4* __restrict__ Bp,
    const float* __restrict__ bias, void* __restrict__ C,
    int M, int Mstore, int ldc, int act, int outfmt) {
  static_assert(KPAD % 64 == 0, "KPAD must be a multiple of 64");
  __shared__ unsigned short As[128 * 72];
  int tid = threadIdx.x;
  int lane = tid & 63;
  int wave = tid >> 6;
  int quad = lane >> 4, m16 = lane & 15;
  int rbase = blockIdx.x * 128;
  int wrow = wave * 32;

  f32x4 acc[2][NT];
#pragma unroll
  for (int mt = 0; mt < 2; ++mt)
#pragma unroll
    for (int nt = 0; nt < NT; ++nt)
      acc[mt][nt] = (f32x4){0.f, 0.f, 0.f, 0.f};

  for (int k0 = 0; k0 < KPAD; k0 += 64) {
    if constexpr (sizeof(AT) == 2) {
      int r0 = tid >> 3, q = tid & 7;
#pragma unroll
      for (int it = 0; it < 4; ++it) {
        int r = r0 + it * 32;
        int row = rbase + r;
        uint4 v = make_uint4(0u, 0u, 0u, 0u);
        if (row < N_NODES)
          v = *(const uint4*)((const unsigned short*)A + (size_t)row * KPAD + k0 + q * 8);
        *(uint4*)&As[r * 72 + q * 8] = v;
      }
    } else {
      int r0 = tid >> 4, fq = tid & 15;
#pragma unroll
      for (int it = 0; it < 8; ++it) {
        int r = r0 + it * 16;
        int row = rbase + r;
        float4 v = make_float4(0.f, 0.f, 0.f, 0.f);
        if (row < N_NODES)
          v = *(const float4*)((const float*)A + (size_t)row * KPAD + k0 + fq * 4);
        unsigned short p[4] = {f2bf(v.x), f2bf(v.y), f2bf(v.z), f2bf(v.w)};
        *(uint2*)&As[r * 72 + fq * 4] = *(uint2*)p;
      }
    }
    __syncthreads();
#pragma unroll
    for (int s = 0; s < 2; ++s) {
      int kt = (k0 >> 5) + s;
      bf16x8 a0 = *(const bf16x8*)&As[(wrow + m16) * 72 + s * 32 + quad * 8];
      bf16x8 a1 = *(const bf16x8*)&As[(wrow + 16 + m16) * 72 + s * 32 + quad * 8];
#pragma unroll
      for (int nt = 0; nt < NT; ++nt) {
        uint4 bw = Bp[(size_t)(kt * NT + nt) * 64 + lane];
        bf16x8 b = *(const bf16x8*)&bw;
        acc[0][nt] = __builtin_amdgcn_mfma_f32_16x16x32_bf16(a0, b, acc[0][nt], 0, 0, 0);
        acc[1][nt] = __builtin_amdgcn_mfma_f32_16x16x32_bf16(a1, b, acc[1][nt], 0, 0, 0);
      }
    }
    __syncthreads();
  }

#pragma unroll
  for (int mt = 0; mt < 2; ++mt)
#pragma unroll
    for (int nt = 0; nt < NT; ++nt)
#pragma unroll
      for (int i = 0; i < 4; ++i) {
        int row = rbase + wrow + mt * 16 + quad * 4 + i;
        int col = nt * 16 + m16;
        if (row >= N_NODES || col >= Mstore) continue;
        float c = acc[mt][nt][i];
        if (col < M) {
          if (bias) c += bias[col];
          if (act) c = tanhf(c);
        } else {
          c = 0.f;
        }
        if (outfmt == 0)
          ((float*)C)[(size_t)row * ldc + col] = c;
        else if (outfmt == 1)
          ((unsigned short*)C)[(size_t)row * ldc + col] = f2bf(c);
        else
          ((unsigned short*)C)[(((size_t)(col >> 4) * N_NODES + row) << 4) + (col & 15)] = f2bf(c);
      }
}

// ---------------- chunked SPMM ---------------------------------------------
// layout [chunk][N][16] bf16 (32 B rows). chunk = blockIdx&7 (XCD affinity).
// 16-lane group per dest row: 4 edge-slots x 4 parts (8 B each).
__global__ __launch_bounds__(256) void spmm_chunk_kernel(
    const int* __restrict__ rowptr, const unsigned* __restrict__ ep,
    const unsigned short* __restrict__ xin, unsigned short* __restrict__ xout,
    int nchunks) {
  int chunk = blockIdx.x & 7;
  if (chunk >= nchunks) return;
  int slice = blockIdx.x >> 3;
  int tid = threadIdx.x;
  int r = slice * 16 + (tid >> 4);
  if (r >= N_NODES) return;
  int il = tid & 15;
  int esub = il >> 2, part = il & 3;
  int e0 = rowptr[r], e1 = rowptr[r + 1];
  const uint2* tin = (const uint2*)(xin + ((size_t)chunk * N_NODES) * 16);

  float a0 = 0.f, a1 = 0.f, a2 = 0.f, a3 = 0.f;
  float b0 = 0.f, b1 = 0.f, b2 = 0.f, b3 = 0.f;
  int e = e0 + esub;
  for (; e + 4 < e1; e += 8) {
    unsigned u0 = __builtin_nontemporal_load(ep + e);
    unsigned u1 = __builtin_nontemporal_load(ep + e + 4);
    float v0 = (float)(u0 & 0x7fffu) * (1.f / 32767.f);
    float v1 = (float)(u1 & 0x7fffu) * (1.f / 32767.f);
    uint2 d0 = tin[(size_t)(u0 >> 15) * 4 + part];
    uint2 d1 = tin[(size_t)(u1 >> 15) * 4 + part];
    a0 = fmaf(v0, __uint_as_float(d0.x << 16), a0);
    a1 = fmaf(v0, __uint_as_float(d0.x & 0xffff0000u), a1);
    a2 = fmaf(v0, __uint_as_float(d0.y << 16), a2);
    a3 = fmaf(v0, __uint_as_float(d0.y & 0xffff0000u), a3);
    b0 = fmaf(v1, __uint_as_float(d1.x << 16), b0);
    b1 = fmaf(v1, __uint_as_float(d1.x & 0xffff0000u), b1);
    b2 = fmaf(v1, __uint_as_float(d1.y << 16), b2);
    b3 = fmaf(v1, __uint_as_float(d1.y & 0xffff0000u), b3);
  }
  if (e < e1) {
    unsigned u0 = __builtin_nontemporal_load(ep + e);
    float v0 = (float)(u0 & 0x7fffu) * (1.f / 32767.f);
    uint2 d0 = tin[(size_t)(u0 >> 15) * 4 + part];
    a0 = fmaf(v0, __uint_as_float(d0.x << 16), a0);
    a1 = fmaf(v0, __uint_as_float(d0.x & 0xffff0000u), a1);
    a2 = fmaf(v0, __uint_as_float(d0.y << 16), a2);
    a3 = fmaf(v0, __uint_as_float(d0.y & 0xffff0000u), a3);
  }
  a0 += b0; a1 += b1; a2 += b2; a3 += b3;
  // reduce over the 4 edge-slots (lanes xor 4, 8 within the 16-lane group)
  a0 += __shfl_xor(a0, 4, 64); a0 += __shfl_xor(a0, 8, 64);
  a1 += __shfl_xor(a1, 4, 64); a1 += __shfl_xor(a1, 8, 64);
  a2 += __shfl_xor(a2, 4, 64); a2 += __shfl_xor(a2, 8, 64);
  a3 += __shfl_xor(a3, 4, 64); a3 += __shfl_xor(a3, 8, 64);
  if (esub == 0) {
    unsigned lo = (unsigned)f2bf(a0) | ((unsigned)f2bf(a1) << 16);
    unsigned hi = (unsigned)f2bf(a2) | ((unsigned)f2bf(a3) << 16);
    unsigned long long w = (unsigned long long)lo | ((unsigned long long)hi << 32);
    unsigned long long* dst = (unsigned long long*)(xout + ((size_t)chunk * N_NODES) * 16) +
                              ((size_t)r * 4 + part);
    __builtin_nontemporal_store(w, dst);
  }
}

// -------- bias + LayerNorm + tanh (chunked bf16 in, flat bf16 out) ---------
template <int F, int LDOUT>
__global__ __launch_bounds__(256) void bias_ln_tanh_kernel(
    const unsigned short* __restrict__ in, const float* __restrict__ bias,
    const float* __restrict__ g, const float* __restrict__ b,
    unsigned short* __restrict__ out) {
  int wid = threadIdx.x >> 6, lane = threadIdx.x & 63;
  int r = blockIdx.x * 4 + wid;
  if (r >= N_NODES) return;
  float x0 = 0.f, x1 = 0.f;
  if (lane < F)
    x0 = bf2f(in[(((size_t)(lane >> 4) * N_NODES + r) << 4) + (lane & 15)]) + bias[lane];
  int c2 = lane + 64;
  if (c2 < F)
    x1 = bf2f(in[(((size_t)(c2 >> 4) * N_NODES + r) << 4) + (c2 & 15)]) + bias[c2];
  float s = x0 + x1, s2 = x0 * x0 + x1 * x1;
  for (int o = 32; o > 0; o >>= 1) {
    s  += __shfl_down(s, o, 64);
    s2 += __shfl_down(s2, o, 64);
  }
  s = __shfl(s, 0, 64); s2 = __shfl(s2, 0, 64);
  const float invF = 1.0f / (float)F;
  float mu = s * invF;
  float var = s2 * invF - mu * mu;
  float rs = rsqrtf(var + 1e-5f);
  if (lane < F)
    out[(size_t)r * LDOUT + lane] = f2bf(tanhf((x0 - mu) * rs * g[lane] + b[lane]));
  if (c2 < F)
    out[(size_t)r * LDOUT + c2] = f2bf(tanhf((x1 - mu) * rs * g[c2] + b[c2]));
  else if (c2 < LDOUT)
    out[(size_t)r * LDOUT + c2] = 0;
}

// ---------------------------------------------------------------------------
extern "C" void kernel_launch(void* const* d_in, const int* in_sizes, int n_in,
                              void* d_out, int out_size, void* d_ws,
                              size_t ws_size, hipStream_t stream) {
  const float* x        = (const float*)d_in[0];
  const float* adj_vals = (const float*)d_in[1];
  const float* bn_g     = (const float*)d_in[2];
  const float* bn_b     = (const float*)d_in[3];
  const float* W_in     = (const float*)d_in[4];
  const float* b_in     = (const float*)d_in[5];
  const float* W1       = (const float*)d_in[6];
  const float* b1       = (const float*)d_in[7];
  const float* ln1_g    = (const float*)d_in[8];
  const float* ln1_b    = (const float*)d_in[9];
  const float* W2       = (const float*)d_in[10];
  const float* b2       = (const float*)d_in[11];
  const float* ln2_g    = (const float*)d_in[12];
  const float* ln2_b    = (const float*)d_in[13];
  const float* W_out    = (const float*)d_in[14];
  const float* b_out    = (const float*)d_in[15];
  const int*   adj_rows = (const int*)d_in[16];
  const int*   adj_cols = (const int*)d_in[17];
  float* out = (float*)d_out;

  // workspace layout
  char* wsb = (char*)d_ws;
  size_t off = 0;
  auto alloc = [&](size_t bytes) { void* p = wsb + off; off += (bytes + 255) & ~255ull; return p; };
  float* bn_sums = (float*)alloc(512 * 4);
  float* Wf      = (float*)alloc(35840 * 4);
  float* bf      = (float*)alloc(144 * 4);
  int*   rowptr  = (int*)alloc(100016 * 4);
  uint4* Bp1 = (uint4*)alloc(8 * 10 * 64 * 16);  // K=256, NT=10
  uint4* Bp2 = (uint4*)alloc(6 * 8 * 64 * 16);   // K=192, NT=8 (real K=140, M pad 128)
  uint4* Bp3 = (uint4*)alloc(4 * 7 * 64 * 16);   // K=128, NT=7 (M pad 112)
  uint4* Bp4 = (uint4*)alloc(4 * 4 * 64 * 16);   // K=128, NT=4
  unsigned* epk = (unsigned*)alloc((size_t)E_EDGES * 4);
  // H region (38.4 MB): h1 [N,192] -> cb_b -> lnb [N,128] -> cb_b -> lnb2
  unsigned short* H    = (unsigned short*)alloc((size_t)N_NODES * 192 * 2);
  unsigned short* cb_a = (unsigned short*)alloc((size_t)N_NODES * 128 * 2);  // chunked [8][N][16]
  unsigned short* cb_b = H;   // chunked alias (h1/lnb dead when used)

  hipMemsetAsync(bn_sums, 0, 512 * sizeof(float), stream);
  hipMemsetAsync(H, 0, (size_t)N_NODES * 192 * 2, stream);  // h1 cols 160..191 = 0
  bn_stats_kernel<<<1024, 256, 0, stream>>>(x, bn_sums);
  fold_bn_kernel<<<140, 256, 0, stream>>>(bn_sums, bn_g, bn_b, W_in, b_in, Wf, bf);
  build_rowptr_kernel<<<(N_NODES + 256) / 256, 256, 0, stream>>>(adj_rows, rowptr);
  pack_edges_kernel<<<(E_EDGES + 255) / 256, 256, 0, stream>>>(adj_cols, adj_vals, epk);
  pack_w_kernel<<<(8 * 10 * 64 + 255) / 256, 256, 0, stream>>>(Wf,    Bp1, 256, 140, 10, 8 * 10 * 64);
  pack_w_kernel<<<(6 * 8 * 64 + 255) / 256, 256, 0, stream>>>(W1,    Bp2, 140, 120, 8,  6 * 8 * 64);
  pack_w_kernel<<<(4 * 7 * 64 + 255) / 256, 256, 0, stream>>>(W2,    Bp3, 120, 100, 7,  4 * 7 * 64);
  pack_w_kernel<<<(4 * 4 * 64 + 255) / 256, 256, 0, stream>>>(W_out, Bp4, 100, 64,  4,  4 * 4 * 64);

  const int gemm_grid = (N_NODES + 127) / 128;  // 782
  const int spmm_grid = 8 * (N_NODES / 16);     // 8 chunk-slots x 6250 slices
  const int ln_grid   = (N_NODES + 3) / 4;

  // h1 = tanh(bn(x) @ Wf + bf)  [N,192] bf16 flat
  mfma_gemm_kernel<256, 10, float><<<gemm_grid, 256, 0, stream>>>(
      x, Bp1, bf, H, 140, 160, 192, 1, 1);
  // cb_a = h1 @ W1 (chunked, cols 120..127 = 0)
  mfma_gemm_kernel<192, 8, unsigned short><<<gemm_grid, 256, 0, stream>>>(
      H, Bp2, nullptr, cb_a, 120, 128, 0, 0, 2);
  // 4 hops, 8 chunks (F=128 incl. zero pad)
  spmm_chunk_kernel<<<spmm_grid, 256, 0, stream>>>(rowptr, epk, cb_a, cb_b, 8);
  spmm_chunk_kernel<<<spmm_grid, 256, 0, stream>>>(rowptr, epk, cb_b, cb_a, 8);
  spmm_chunk_kernel<<<spmm_grid, 256, 0, stream>>>(rowptr, epk, cb_a, cb_b, 8);
  spmm_chunk_kernel<<<spmm_grid, 256, 0, stream>>>(rowptr, epk, cb_b, cb_a, 8);
  // lnb = tanh(LN(cb_a + b1))  flat [N,128], cols 120..127 = 0
  bias_ln_tanh_kernel<120, 128><<<ln_grid, 256, 0, stream>>>(cb_a, b1, ln1_g, ln1_b, H);
  // cb_a = lnb @ W2 (chunked, 7 chunks, cols 100..111 = 0)
  mfma_gemm_kernel<128, 7, unsigned short><<<gemm_grid, 256, 0, stream>>>(
      H, Bp3, nullptr, cb_a, 100, 112, 0, 0, 2);
  // 4 hops, 7 chunks
  spmm_chunk_kernel<<<spmm_grid, 256, 0, stream>>>(rowptr, epk, cb_a, cb_b, 7);
  spmm_chunk_kernel<<<spmm_grid, 256, 0, stream>>>(rowptr, epk, cb_b, cb_a, 7);
  spmm_chunk_kernel<<<spmm_grid, 256, 0, stream>>>(rowptr, epk, cb_a, cb_b, 7);
  spmm_chunk_kernel<<<spmm_grid, 256, 0, stream>>>(rowptr, epk, cb_b, cb_a, 7);
  // lnb2 = tanh(LN(cb_a + b2))  flat [N,128], cols 100..127 = 0
  bias_ln_tanh_kernel<100, 128><<<ln_grid, 256, 0, stream>>>(cb_a, b2, ln2_g, ln2_b, H);
  // out = lnb2 @ W_out + b_out  [N,64] fp32
  mfma_gemm_kernel<128, 4, unsigned short><<<gemm_grid, 256, 0, stream>>>(
      H, Bp4, b_out, out, 64, 64, 64, 0, 0);
}

// Round 6
// 2159.022 us; speedup vs baseline: 1.0866x; 1.0866x over previous
//
#include <hip/hip_runtime.h>
#include <hip/hip_bf16.h>
#include <math.h>

#define N_NODES 100000
#define E_EDGES 3200000
#define IN_DIM  256

typedef __attribute__((ext_vector_type(8))) short bf16x8;
typedef __attribute__((ext_vector_type(4))) float f32x4;

// ---- bf16 helpers ---------------------------------------------------------
__device__ __forceinline__ unsigned short f2bf(float f) {
  unsigned u = __float_as_uint(f);
  u += 0x7fffu + ((u >> 16) & 1u);   // RTNE
  return (unsigned short)(u >> 16);
}
__device__ __forceinline__ float bf2f(unsigned short h) {
  return __uint_as_float(((unsigned)h) << 16);
}

// ---------------- BN column stats ------------------------------------------
__global__ __launch_bounds__(256) void bn_stats_kernel(
    const float* __restrict__ x, float* __restrict__ sums) {
  int c = threadIdx.x;
  float s = 0.f, s2 = 0.f;
  for (int r = blockIdx.x; r < N_NODES; r += gridDim.x) {
    float v = x[(size_t)r * IN_DIM + c];
    s += v; s2 += v * v;
  }
  atomicAdd(&sums[c], s);
  atomicAdd(&sums[256 + c], s2);
}

// ------------- fold BN affine into W_in / b_in ----------------------------
__global__ __launch_bounds__(256) void fold_bn_kernel(
    const float* __restrict__ sums, const float* __restrict__ bn_g,
    const float* __restrict__ bn_b, const float* __restrict__ W_in,
    const float* __restrict__ b_in, float* __restrict__ Wf,
    float* __restrict__ bf) {
  int j = blockIdx.x;   // out col 0..139
  int c = threadIdx.x;  // in col 0..255
  const float invN = 1.0f / (float)N_NODES;
  float mu  = sums[c] * invN;
  float var = sums[256 + c] * invN - mu * mu;
  float s   = bn_g[c] * rsqrtf(var + 1e-5f);
  float t   = bn_b[c] - mu * s;
  float w   = W_in[(size_t)c * 140 + j];
  Wf[(size_t)c * 140 + j] = s * w;
  float v = t * w;
  for (int o = 32; o > 0; o >>= 1) v += __shfl_down(v, o, 64);
  __shared__ float red[4];
  int wid = threadIdx.x >> 6, lane = threadIdx.x & 63;
  if (lane == 0) red[wid] = v;
  __syncthreads();
  if (threadIdx.x == 0)
    bf[j] = b_in[j] + red[0] + red[1] + red[2] + red[3];
}

// ---------------- CSR row_ptr from sorted rows -----------------------------
__global__ __launch_bounds__(256) void build_rowptr_kernel(
    const int* __restrict__ rows, int* __restrict__ rowptr) {
  int r = blockIdx.x * 256 + threadIdx.x;
  if (r > N_NODES) return;
  int lo = 0, hi = E_EDGES;
  while (lo < hi) {
    int mid = (lo + hi) >> 1;
    if (rows[mid] < r) lo = mid + 1; else hi = mid;
  }
  rowptr[r] = lo;
}

// ---------------- pack edges: col<<15 | q15(val) ---------------------------
__global__ __launch_bounds__(256) void pack_edges_kernel(
    const int* __restrict__ cols, const float* __restrict__ vals,
    unsigned* __restrict__ ep) {
  int e = blockIdx.x * 256 + threadIdx.x;
  if (e >= E_EDGES) return;
  unsigned q = (unsigned)(vals[e] * 32767.f + 0.5f);
  if (q > 32767u) q = 32767u;
  ep[e] = ((unsigned)cols[e] << 15) | q;
}

// ------- pack fp32 W[K,M] into MFMA B-fragment order, bf16, zero-padded ----
__global__ __launch_bounds__(256) void pack_w_kernel(
    const float* __restrict__ W, uint4* __restrict__ Bp, int K, int M, int NT,
    int total) {
  int id = blockIdx.x * 256 + threadIdx.x;
  if (id >= total) return;
  int lane = id & 63;
  int nt = (id >> 6) % NT;
  int kt = id / (64 * NT);
  int n = nt * 16 + (lane & 15);
  int kbase = kt * 32 + (lane >> 4) * 8;
  unsigned short v[8];
#pragma unroll
  for (int j = 0; j < 8; ++j) {
    int k = kbase + j;
    v[j] = (k < K && n < M) ? f2bf(W[(size_t)k * M + n]) : (unsigned short)0;
  }
  Bp[id] = *(uint4*)v;
}

// ---------------- MFMA bf16 GEMM -------------------------------------------
// outfmt: 0 fp32 flat, 1 bf16 flat, 2 bf16 chunked [chunk][N][16]
template <int KPAD, int NT, typename AT>
__global__ __launch_bounds__(256) void mfma_gemm_kernel(
    const AT* __restrict__ A, const uint4* __restrict__ Bp,
    const float* __restrict__ bias, void* __restrict__ C,
    int M, int Mstore, int ldc, int act, int outfmt) {
  static_assert(KPAD % 64 == 0, "KPAD must be a multiple of 64");
  __shared__ unsigned short As[128 * 72];
  int tid = threadIdx.x;
  int lane = tid & 63;
  int wave = tid >> 6;
  int quad = lane >> 4, m16 = lane & 15;
  int rbase = blockIdx.x * 128;
  int wrow = wave * 32;

  f32x4 acc[2][NT];
#pragma unroll
  for (int mt = 0; mt < 2; ++mt)
#pragma unroll
    for (int nt = 0; nt < NT; ++nt)
      acc[mt][nt] = (f32x4){0.f, 0.f, 0.f, 0.f};

  for (int k0 = 0; k0 < KPAD; k0 += 64) {
    if constexpr (sizeof(AT) == 2) {
      int r0 = tid >> 3, q = tid & 7;
#pragma unroll
      for (int it = 0; it < 4; ++it) {
        int r = r0 + it * 32;
        int row = rbase + r;
        uint4 v = make_uint4(0u, 0u, 0u, 0u);
        if (row < N_NODES)
          v = *(const uint4*)((const unsigned short*)A + (size_t)row * KPAD + k0 + q * 8);
        *(uint4*)&As[r * 72 + q * 8] = v;
      }
    } else {
      int r0 = tid >> 4, fq = tid & 15;
#pragma unroll
      for (int it = 0; it < 8; ++it) {
        int r = r0 + it * 16;
        int row = rbase + r;
        float4 v = make_float4(0.f, 0.f, 0.f, 0.f);
        if (row < N_NODES)
          v = *(const float4*)((const float*)A + (size_t)row * KPAD + k0 + fq * 4);
        unsigned short p[4] = {f2bf(v.x), f2bf(v.y), f2bf(v.z), f2bf(v.w)};
        *(uint2*)&As[r * 72 + fq * 4] = *(uint2*)p;
      }
    }
    __syncthreads();
#pragma unroll
    for (int s = 0; s < 2; ++s) {
      int kt = (k0 >> 5) + s;
      bf16x8 a0 = *(const bf16x8*)&As[(wrow + m16) * 72 + s * 32 + quad * 8];
      bf16x8 a1 = *(const bf16x8*)&As[(wrow + 16 + m16) * 72 + s * 32 + quad * 8];
#pragma unroll
      for (int nt = 0; nt < NT; ++nt) {
        uint4 bw = Bp[(size_t)(kt * NT + nt) * 64 + lane];
        bf16x8 b = *(const bf16x8*)&bw;
        acc[0][nt] = __builtin_amdgcn_mfma_f32_16x16x32_bf16(a0, b, acc[0][nt], 0, 0, 0);
        acc[1][nt] = __builtin_amdgcn_mfma_f32_16x16x32_bf16(a1, b, acc[1][nt], 0, 0, 0);
      }
    }
    __syncthreads();
  }

#pragma unroll
  for (int mt = 0; mt < 2; ++mt)
#pragma unroll
    for (int nt = 0; nt < NT; ++nt)
#pragma unroll
      for (int i = 0; i < 4; ++i) {
        int row = rbase + wrow + mt * 16 + quad * 4 + i;
        int col = nt * 16 + m16;
        if (row >= N_NODES || col >= Mstore) continue;
        float c = acc[mt][nt][i];
        if (col < M) {
          if (bias) c += bias[col];
          if (act) c = tanhf(c);
        } else {
          c = 0.f;
        }
        if (outfmt == 0)
          ((float*)C)[(size_t)row * ldc + col] = c;
        else if (outfmt == 1)
          ((unsigned short*)C)[(size_t)row * ldc + col] = f2bf(c);
        else
          ((unsigned short*)C)[(((size_t)(col >> 4) * N_NODES + row) << 4) + (col & 15)] = f2bf(c);
      }
}

// ---------------- chunked SPMM, round-4-style gather engine ----------------
// layout [chunk][N][16] bf16 (32 B rows). chunk = blockIdx&7 (XCD affinity).
// 32-lane half-wave per dest row: preload 32 edges coalesced, then 4 unrolled
// iterations x (shfl-broadcast 8 edges, one 32-lane gather = 8 edges x 32 B).
__global__ __launch_bounds__(256) void spmm_chunk_kernel(
    const int* __restrict__ rowptr, const unsigned* __restrict__ ep,
    const unsigned short* __restrict__ xin, unsigned short* __restrict__ xout,
    int nchunks) {
  int chunk = blockIdx.x & 7;
  if (chunk >= nchunks) return;
  int slice = blockIdx.x >> 3;
  int lane = threadIdx.x & 31;
  int r = slice * 8 + (threadIdx.x >> 5);
  if (r >= N_NODES) return;
  int esub = lane >> 2;  // 0..7: edge slot within a gather
  int part = lane & 3;   // 0..3: 8 B piece of the 32 B row
  int e0 = rowptr[r], e1 = rowptr[r + 1];
  const uint2* tin = (const uint2*)(xin + ((size_t)chunk * N_NODES) * 16);

  float a0 = 0.f, a1 = 0.f, a2 = 0.f, a3 = 0.f;
  int e = e0;
  while (e + 32 <= e1) {
    unsigned epl = __builtin_nontemporal_load(ep + e + lane);
#pragma unroll
    for (int j = 0; j < 32; j += 8) {
      unsigned u = __shfl(epl, j + esub, 32);
      float v = (float)(u & 0x7fffu) * (1.f / 32767.f);
      uint2 d = tin[(size_t)(u >> 15) * 4 + part];
      a0 = fmaf(v, __uint_as_float(d.x << 16), a0);
      a1 = fmaf(v, __uint_as_float(d.x & 0xffff0000u), a1);
      a2 = fmaf(v, __uint_as_float(d.y << 16), a2);
      a3 = fmaf(v, __uint_as_float(d.y & 0xffff0000u), a3);
    }
    e += 32;
  }
  int rem = e1 - e;
  if (rem > 0) {
    unsigned epl = (lane < rem) ? ep[e + lane] : 0u;
    for (int j = 0; j < rem; j += 8) {
      unsigned u = __shfl(epl, j + esub, 32);
      bool ok = (j + esub) < rem;
      float v = ok ? (float)(u & 0x7fffu) * (1.f / 32767.f) : 0.f;
      size_t idx = ok ? (size_t)(u >> 15) : 0;
      uint2 d = tin[idx * 4 + part];
      a0 = fmaf(v, __uint_as_float(d.x << 16), a0);
      a1 = fmaf(v, __uint_as_float(d.x & 0xffff0000u), a1);
      a2 = fmaf(v, __uint_as_float(d.y << 16), a2);
      a3 = fmaf(v, __uint_as_float(d.y & 0xffff0000u), a3);
    }
  }
  // reduce over the 8 edge slots (lane bits 2..4)
  a0 += __shfl_xor(a0, 4, 64); a0 += __shfl_xor(a0, 8, 64); a0 += __shfl_xor(a0, 16, 64);
  a1 += __shfl_xor(a1, 4, 64); a1 += __shfl_xor(a1, 8, 64); a1 += __shfl_xor(a1, 16, 64);
  a2 += __shfl_xor(a2, 4, 64); a2 += __shfl_xor(a2, 8, 64); a2 += __shfl_xor(a2, 16, 64);
  a3 += __shfl_xor(a3, 4, 64); a3 += __shfl_xor(a3, 8, 64); a3 += __shfl_xor(a3, 16, 64);
  if (esub == 0) {
    unsigned lo = (unsigned)f2bf(a0) | ((unsigned)f2bf(a1) << 16);
    unsigned hi = (unsigned)f2bf(a2) | ((unsigned)f2bf(a3) << 16);
    unsigned long long w = (unsigned long long)lo | ((unsigned long long)hi << 32);
    unsigned long long* dst = (unsigned long long*)(xout + ((size_t)chunk * N_NODES) * 16) +
                              ((size_t)r * 4 + part);
    __builtin_nontemporal_store(w, dst);
  }
}

// -------- bias + LayerNorm + tanh (chunked bf16 in, flat bf16 out) ---------
template <int F, int LDOUT>
__global__ __launch_bounds__(256) void bias_ln_tanh_kernel(
    const unsigned short* __restrict__ in, const float* __restrict__ bias,
    const float* __restrict__ g, const float* __restrict__ b,
    unsigned short* __restrict__ out) {
  int wid = threadIdx.x >> 6, lane = threadIdx.x & 63;
  int r = blockIdx.x * 4 + wid;
  if (r >= N_NODES) return;
  float x0 = 0.f, x1 = 0.f;
  if (lane < F)
    x0 = bf2f(in[(((size_t)(lane >> 4) * N_NODES + r) << 4) + (lane & 15)]) + bias[lane];
  int c2 = lane + 64;
  if (c2 < F)
    x1 = bf2f(in[(((size_t)(c2 >> 4) * N_NODES + r) << 4) + (c2 & 15)]) + bias[c2];
  float s = x0 + x1, s2 = x0 * x0 + x1 * x1;
  for (int o = 32; o > 0; o >>= 1) {
    s  += __shfl_down(s, o, 64);
    s2 += __shfl_down(s2, o, 64);
  }
  s = __shfl(s, 0, 64); s2 = __shfl(s2, 0, 64);
  const float invF = 1.0f / (float)F;
  float mu = s * invF;
  float var = s2 * invF - mu * mu;
  float rs = rsqrtf(var + 1e-5f);
  if (lane < F)
    out[(size_t)r * LDOUT + lane] = f2bf(tanhf((x0 - mu) * rs * g[lane] + b[lane]));
  if (c2 < F)
    out[(size_t)r * LDOUT + c2] = f2bf(tanhf((x1 - mu) * rs * g[c2] + b[c2]));
  else if (c2 < LDOUT)
    out[(size_t)r * LDOUT + c2] = 0;
}

// ---------------------------------------------------------------------------
extern "C" void kernel_launch(void* const* d_in, const int* in_sizes, int n_in,
                              void* d_out, int out_size, void* d_ws,
                              size_t ws_size, hipStream_t stream) {
  const float* x        = (const float*)d_in[0];
  const float* adj_vals = (const float*)d_in[1];
  const float* bn_g     = (const float*)d_in[2];
  const float* bn_b     = (const float*)d_in[3];
  const float* W_in     = (const float*)d_in[4];
  const float* b_in     = (const float*)d_in[5];
  const float* W1       = (const float*)d_in[6];
  const float* b1       = (const float*)d_in[7];
  const float* ln1_g    = (const float*)d_in[8];
  const float* ln1_b    = (const float*)d_in[9];
  const float* W2       = (const float*)d_in[10];
  const float* b2       = (const float*)d_in[11];
  const float* ln2_g    = (const float*)d_in[12];
  const float* ln2_b    = (const float*)d_in[13];
  const float* W_out    = (const float*)d_in[14];
  const float* b_out    = (const float*)d_in[15];
  const int*   adj_rows = (const int*)d_in[16];
  const int*   adj_cols = (const int*)d_in[17];
  float* out = (float*)d_out;

  // workspace layout
  char* wsb = (char*)d_ws;
  size_t off = 0;
  auto alloc = [&](size_t bytes) { void* p = wsb + off; off += (bytes + 255) & ~255ull; return p; };
  float* bn_sums = (float*)alloc(512 * 4);
  float* Wf      = (float*)alloc(35840 * 4);
  float* bf      = (float*)alloc(144 * 4);
  int*   rowptr  = (int*)alloc(100016 * 4);
  uint4* Bp1 = (uint4*)alloc(8 * 10 * 64 * 16);  // K=256, NT=10
  uint4* Bp2 = (uint4*)alloc(6 * 8 * 64 * 16);   // K=192, NT=8 (real K=140, M pad 128)
  uint4* Bp3 = (uint4*)alloc(4 * 7 * 64 * 16);   // K=128, NT=7 (M pad 112)
  uint4* Bp4 = (uint4*)alloc(4 * 4 * 64 * 16);   // K=128, NT=4
  unsigned* epk = (unsigned*)alloc((size_t)E_EDGES * 4);
  unsigned short* H    = (unsigned short*)alloc((size_t)N_NODES * 192 * 2);
  unsigned short* cb_a = (unsigned short*)alloc((size_t)N_NODES * 128 * 2);  // chunked [8][N][16]
  unsigned short* cb_b = H;   // chunked alias (h1/lnb dead when used)

  hipMemsetAsync(bn_sums, 0, 512 * sizeof(float), stream);
  hipMemsetAsync(H, 0, (size_t)N_NODES * 192 * 2, stream);  // h1 cols 160..191 = 0
  bn_stats_kernel<<<1024, 256, 0, stream>>>(x, bn_sums);
  fold_bn_kernel<<<140, 256, 0, stream>>>(bn_sums, bn_g, bn_b, W_in, b_in, Wf, bf);
  build_rowptr_kernel<<<(N_NODES + 256) / 256, 256, 0, stream>>>(adj_rows, rowptr);
  pack_edges_kernel<<<(E_EDGES + 255) / 256, 256, 0, stream>>>(adj_cols, adj_vals, epk);
  pack_w_kernel<<<(8 * 10 * 64 + 255) / 256, 256, 0, stream>>>(Wf,    Bp1, 256, 140, 10, 8 * 10 * 64);
  pack_w_kernel<<<(6 * 8 * 64 + 255) / 256, 256, 0, stream>>>(W1,    Bp2, 140, 120, 8,  6 * 8 * 64);
  pack_w_kernel<<<(4 * 7 * 64 + 255) / 256, 256, 0, stream>>>(W2,    Bp3, 120, 100, 7,  4 * 7 * 64);
  pack_w_kernel<<<(4 * 4 * 64 + 255) / 256, 256, 0, stream>>>(W_out, Bp4, 100, 64,  4,  4 * 4 * 64);

  const int gemm_grid = (N_NODES + 127) / 128;  // 782
  const int spmm_grid = 8 * ((N_NODES + 7) / 8);  // 8 chunk-slots x 12500 slices
  const int ln_grid   = (N_NODES + 3) / 4;

  // h1 = tanh(bn(x) @ Wf + bf)  [N,192] bf16 flat
  mfma_gemm_kernel<256, 10, float><<<gemm_grid, 256, 0, stream>>>(
      x, Bp1, bf, H, 140, 160, 192, 1, 1);
  // cb_a = h1 @ W1 (chunked, cols 120..127 = 0)
  mfma_gemm_kernel<192, 8, unsigned short><<<gemm_grid, 256, 0, stream>>>(
      H, Bp2, nullptr, cb_a, 120, 128, 0, 0, 2);
  // 4 hops, 8 chunks (F=128 incl. zero pad)
  spmm_chunk_kernel<<<spmm_grid, 256, 0, stream>>>(rowptr, epk, cb_a, cb_b, 8);
  spmm_chunk_kernel<<<spmm_grid, 256, 0, stream>>>(rowptr, epk, cb_b, cb_a, 8);
  spmm_chunk_kernel<<<spmm_grid, 256, 0, stream>>>(rowptr, epk, cb_a, cb_b, 8);
  spmm_chunk_kernel<<<spmm_grid, 256, 0, stream>>>(rowptr, epk, cb_b, cb_a, 8);
  // lnb = tanh(LN(cb_a + b1))  flat [N,128], cols 120..127 = 0
  bias_ln_tanh_kernel<120, 128><<<ln_grid, 256, 0, stream>>>(cb_a, b1, ln1_g, ln1_b, H);
  // cb_a = lnb @ W2 (chunked, 7 chunks, cols 100..111 = 0)
  mfma_gemm_kernel<128, 7, unsigned short><<<gemm_grid, 256, 0, stream>>>(
      H, Bp3, nullptr, cb_a, 100, 112, 0, 0, 2);
  // 4 hops, 7 chunks
  spmm_chunk_kernel<<<spmm_grid, 256, 0, stream>>>(rowptr, epk, cb_a, cb_b, 7);
  spmm_chunk_kernel<<<spmm_grid, 256, 0, stream>>>(rowptr, epk, cb_b, cb_a, 7);
  spmm_chunk_kernel<<<spmm_grid, 256, 0, stream>>>(rowptr, epk, cb_a, cb_b, 7);
  spmm_chunk_kernel<<<spmm_grid, 256, 0, stream>>>(rowptr, epk, cb_b, cb_a, 7);
  // lnb2 = tanh(LN(cb_a + b2))  flat [N,128], cols 100..127 = 0
  bias_ln_tanh_kernel<100, 128><<<ln_grid, 256, 0, stream>>>(cb_a, b2, ln2_g, ln2_b, H);
  // out = lnb2 @ W_out + b_out  [N,64] fp32
  mfma_gemm_kernel<128, 4, unsigned short><<<gemm_grid, 256, 0, stream>>>(
      H, Bp4, b_out, out, 64, 64, 64, 0, 0);
}